// Round 5
// baseline (87.370 us; speedup 1.0000x reference)
//
#include <hip/hip_runtime.h>

// Problem constants
#define BB 8
#define CIN 16
#define COUT 64
#define HH 32
#define WW 32
#define PH 34
#define PW 34
#define PPLANE (PH * PW) // 1156

// f(d) = max(sp(clip(d/0.075))^2 - sp(clip((d-0.1)/0.075))^2, 0), sp=log1p(exp).
// Exactly 0 for d >= 1.6 (both args clip to 20 -> cancel); < 2e-9 for d <= -0.75.
// LUT: 2048 x (val, slope) float2 over [-0.75, 1.65], linear interp.
#define LUT_N 2048
#define LUT_LO (-0.75f)
#define LUT_STEP (2.4f / (float)LUT_N)          /* 0.001171875 */
#define LUT_INVSTEP ((float)LUT_N / 2.4f)        /* 853.3333 */
#define LUT_BIAS 640.0f                          /* -LUT_LO * LUT_INVSTEP = 0.75*2048/2.4 */
#define LUT_TMAX 2046.999f
// final scale: ALPHA * R (times runtime `scale`); LUT stores raw sp^2 units
#define OUT_SCALE (0.05625f * 0.1f)

__device__ __forceinline__ float lut_f(float d) {
    const float C = 13.333333f; // 1/0.075
    float a1 = fminf(fmaxf(d * C, -50.0f), 20.0f);
    float a2 = fminf(fmaxf((d - 0.1f) * C, -50.0f), 20.0f);
    float s1 = log1pf(expf(a1));
    float s2 = log1pf(expf(a2));
    return fmaxf(s1 * s1 - s2 * s2, 0.0f);
}

// Merged init: blocks 0..577 pad x into xp ([8][16][34][34]); block 578 builds LUT.
__global__ __launch_bounds__(256) void init_kernel(const float* __restrict__ x,
                                                   float* __restrict__ xp,
                                                   float2* __restrict__ lut_g) {
    if (blockIdx.x < 578) {
        int idx = blockIdx.x * 256 + threadIdx.x; // 578*256 = 147968 exactly
        int c = idx / PPLANE;
        int r = idx - c * PPLANE;
        int y = r / PW;
        int xc = r - y * PW;
        float v = 0.0f;
        if (y >= 1 && y <= HH && xc >= 1 && xc <= WW) {
            v = x[c * (HH * WW) + (y - 1) * WW + (xc - 1)];
        }
        xp[idx] = v;
    } else {
        for (int i = threadIdx.x; i < LUT_N; i += 256) {
            float d0 = LUT_LO + (float)i * LUT_STEP;
            float v0 = lut_f(d0);
            float v1 = lut_f(d0 + LUT_STEP);
            lut_g[i] = make_float2(v0, v1 - v0);
        }
    }
}

__device__ __forceinline__ void load9(const float* __restrict__ p, float* v) {
#pragma unroll
    for (int dy = 0; dy < 3; ++dy)
#pragma unroll
        for (int dx = 0; dx < 3; ++dx)
            v[dy * 3 + dx] = p[dy * PW + dx];
}

// Branchless: every tap does one interp'd LDS lookup. Out-of-window lanes clamp
// to boundary entries (same-address broadcast, conflict-free, value ~0).
__device__ __forceinline__ void compute9(const float* v, const float* __restrict__ sth,
                                         const float2* __restrict__ lut, float* acc) {
    float th[9];
#pragma unroll
    for (int j = 0; j < 9; ++j) th[j] = sth[j];
#pragma unroll
    for (int k = 0; k < 9; ++k) {
        float d = v[k] - th[k];
        float t = fmaf(d, LUT_INVSTEP, LUT_BIAS);
        t = fminf(fmaxf(t, 0.0f), LUT_TMAX);
        int i = (int)t;
        float fr = t - (float)i;
        float2 e = lut[i];
        acc[k % 3] += fmaf(fr, e.y, e.x);
    }
}

// One co per thread, 2048 blocks = b(8) x tile(4) x co(64); co fastest so
// consecutive blocks share the same x tile in L1/L2. 8 waves/SIMD for TLP.
__global__ __launch_bounds__(256, 8) void ekv_kernel(const float* __restrict__ xp,
                                                     const float2* __restrict__ lut_g,
                                                     const float* __restrict__ theta,
                                                     const float* __restrict__ scale,
                                                     float* __restrict__ out) {
    int bid = blockIdx.x;
    int co = bid & 63;
    int tile = (bid >> 6) & 3;
    int b = bid >> 8;

    int t = threadIdx.x;
    int ow = t & 31;
    int oh = tile * 8 + (t >> 5);

    __shared__ __align__(16) float2 s_lut[LUT_N]; // 16 KB
    __shared__ __align__(16) float s_th[CIN * 12]; // 768 B

    // LUT global->LDS: 1024 float4, 4 per thread, coalesced (L2-hot after block 0).
    {
        const float4* g = (const float4*)lut_g;
        float4* s = (float4*)s_lut;
#pragma unroll
        for (int i = 0; i < 4; ++i) s[t + i * 256] = g[t + i * 256];
    }
    // Clipped theta for this co, padded to 12 floats/cin.
    if (t < CIN * 12) {
        int cin = t / 12;
        int j = t - cin * 12;
        float v = 0.0f;
        if (j < 9) {
            float th = theta[co * (CIN * 9) + cin * 9 + j];
            v = fminf(fmaxf(th, 1.0f), 8.0f);
        }
        s_th[t] = v;
    }
    __syncthreads();

    float acc[3] = {0.0f, 0.0f, 0.0f};

    // Register ping-pong over cin: prefetch next plane's 9 taps while current
    // plane's 9 LUT-evals run.
    const float* p0 = xp + (size_t)b * (CIN * PPLANE) + oh * PW + ow;
    float va[9], vb[9];
    load9(p0, va);
#pragma unroll 1
    for (int cin = 0; cin < CIN; cin += 2) {
        load9(p0 + (cin + 1) * PPLANE, vb);
        compute9(va, s_th + cin * 12, s_lut, acc);
        int nc = cin + 2 < CIN ? cin + 2 : CIN - 1; // clamp: harmless re-read
        load9(p0 + nc * PPLANE, va);
        compute9(vb, s_th + (cin + 1) * 12, s_lut, acc);
    }

    float sc = scale[0] * (OUT_SCALE);
    out[(((size_t)b * COUT + co) * HH + oh) * WW + ow] =
        (acc[0] + acc[1] + acc[2]) * sc;
}

extern "C" void kernel_launch(void* const* d_in, const int* in_sizes, int n_in,
                              void* d_out, int out_size, void* d_ws, size_t ws_size,
                              hipStream_t stream) {
    const float* x = (const float*)d_in[0];
    const float* theta = (const float*)d_in[1];
    const float* scale = (const float*)d_in[2];
    float* out = (float*)d_out;

    // ws layout: [0,16KB) LUT (float2[2048]); [16KB, ...) padded x (147968 f32)
    float2* lut_g = (float2*)d_ws;
    float* xp = (float*)((char*)d_ws + LUT_N * sizeof(float2));
    (void)ws_size;

    init_kernel<<<579, 256, 0, stream>>>(x, xp, lut_g);
    ekv_kernel<<<BB * 4 * COUT, 256, 0, stream>>>(xp, lut_g, theta, scale, out);
}

// Round 6
// 75.626 us; speedup vs baseline: 1.1553x; 1.1553x over previous
//
#include <hip/hip_runtime.h>

// Problem constants
#define BB 8
#define CIN 16
#define COUT 64
#define HH 32
#define WW 32
#define PH 34
#define PW 34
#define PPLANE (PH * PW) // 1156

// denom = 2*N_EKV*VT = 0.075. Everything pre-scaled into log2-units:
//   xp = x * C,  th' = clip(theta,1,8) * C,  C = log2(e)/0.075
//   b1 = xp - th' = (x-theta)*C;  b2 = b1 - 0.1*C  => e2 = e1 * 2^(-0.1*C)
// Reference clip(a,-50,20) == post-log l = min(log2(1+2^b), B_HI) (fp32-exact:
// b >= B_HI -> log2(1+2^b)==b; b <= -30 -> 1+2^b rounds to 1 -> l=0).
// d >= 1.6: both l's hit B_HI -> cancel exactly (matches reference's clip).
// d <= -0.72 (b1 <= -13.85): f < 5e-9 -> skip via wave-uniform branch.
#define SCALE_C 19.235933878519388f /* (1/0.075)*log2(e) */
#define K2E 0.26359713811472845f    /* 2^(-0.1*SCALE_C) = e^(-4/3) */
#define B_HI 28.85390081777927f     /* 20*log2e */
#define WINLO_S (-13.849872392533959f) /* -0.72 * SCALE_C */
// final scale: ln2^2 * ALPHA * R (times runtime `scale`)
#define OUT_CONST (0.4804530139182014f * 0.05625f * 0.1f)

#define EXP2F(x) __builtin_amdgcn_exp2f(x)
#define LOG2F(x) __builtin_amdgcn_logf(x)

#define NTH (COUT * CIN * 9) // 9216

// blocks 0..577: pad+prescale x into xp ([8][16][34][34]);
// blocks 578..613: prescale clipped theta (9216 elems).
__global__ __launch_bounds__(256) void init_kernel(const float* __restrict__ x,
                                                   const float* __restrict__ theta,
                                                   float* __restrict__ xp,
                                                   float* __restrict__ thp) {
    if (blockIdx.x < 578) {
        int idx = blockIdx.x * 256 + threadIdx.x; // 578*256 = 147968 exactly
        int c = idx / PPLANE;
        int r = idx - c * PPLANE;
        int y = r / PW;
        int xc = r - y * PW;
        float v = 0.0f;
        if (y >= 1 && y <= HH && xc >= 1 && xc <= WW) {
            v = x[c * (HH * WW) + (y - 1) * WW + (xc - 1)] * SCALE_C;
        }
        xp[idx] = v;
    } else {
        int i = (blockIdx.x - 578) * 256 + threadIdx.x;
        if (i < NTH) {
            thp[i] = fminf(fmaxf(theta[i], 1.0f), 8.0f) * SCALE_C;
        }
    }
}

__device__ __forceinline__ void load9(const float* __restrict__ p, float* v) {
#pragma unroll
    for (int dy = 0; dy < 3; ++dy)
#pragma unroll
        for (int dx = 0; dx < 3; ++dx)
            v[dy * 3 + dx] = p[dy * PW + dx];
}

// thp indices are block-uniform -> compiler emits s_load; the sub/cmp use the
// SGPR operand directly. Untaken tap: v_sub + v_cmp + s_cbranch (~3 instrs).
__device__ __forceinline__ void compute9(const float* v, const float* __restrict__ thp,
                                         float* acc) {
#pragma unroll
    for (int k = 0; k < 9; ++k) {
        float b1 = v[k] - thp[k];
        if (__any(b1 > WINLO_S)) {
            float e1 = EXP2F(b1);
            float e2 = e1 * K2E;
            float l1 = fminf(LOG2F(1.0f + e1), B_HI);
            float l2 = fminf(LOG2F(1.0f + e2), B_HI);
            float a = acc[k % 3];
            a = fmaf(l1, l1, a);
            a = fmaf(-l2, l2, a);
            acc[k % 3] = a;
        }
    }
}

// One co per thread, 2048 blocks = b(8) x tile(4) x co(64); co fastest so
// consecutive blocks share the same x tile in L1/L2. No LDS, no barrier;
// 8 blocks/CU -> 8 waves/SIMD. (256,8) caps VGPR at 64 (fits: ~35 live).
__global__ __launch_bounds__(256, 8) void ekv_kernel(const float* __restrict__ xp,
                                                     const float* __restrict__ thp,
                                                     const float* __restrict__ scale,
                                                     float* __restrict__ out) {
    int bid = blockIdx.x;
    int co = bid & 63;
    int tile = (bid >> 6) & 3;
    int b = bid >> 8;

    int t = threadIdx.x;
    int ow = t & 31;
    int oh = tile * 8 + (t >> 5);

    const float* thc = thp + co * (CIN * 9);
    const float* p0 = xp + (size_t)b * (CIN * PPLANE) + oh * PW + ow;

    float acc[3] = {0.0f, 0.0f, 0.0f};

    // Register ping-pong over cin: prefetch next plane's 9 taps while current
    // plane's 9 evals run.
    float va[9], vb[9];
    load9(p0, va);
#pragma unroll 1
    for (int cin = 0; cin < CIN; cin += 2) {
        load9(p0 + (cin + 1) * PPLANE, vb);
        compute9(va, thc + cin * 9, acc);
        int nc = cin + 2 < CIN ? cin + 2 : CIN - 1; // clamp: harmless re-read
        load9(p0 + nc * PPLANE, va);
        compute9(vb, thc + (cin + 1) * 9, acc);
    }

    float sc = scale[0] * (OUT_CONST);
    out[(((size_t)b * COUT + co) * HH + oh) * WW + ow] =
        (acc[0] + acc[1] + acc[2]) * sc;
}

extern "C" void kernel_launch(void* const* d_in, const int* in_sizes, int n_in,
                              void* d_out, int out_size, void* d_ws, size_t ws_size,
                              hipStream_t stream) {
    const float* x = (const float*)d_in[0];
    const float* theta = (const float*)d_in[1];
    const float* scale = (const float*)d_in[2];
    float* out = (float*)d_out;

    // ws layout: [0, 36KB) prescaled theta (9216 f32); then padded x (147968 f32)
    float* thp = (float*)d_ws;
    float* xp = thp + NTH;
    (void)ws_size;

    init_kernel<<<578 + (NTH + 255) / 256, 256, 0, stream>>>(x, theta, xp, thp);
    ekv_kernel<<<BB * 4 * COUT, 256, 0, stream>>>(xp, thp, scale, out);
}

// Round 7
// 74.454 us; speedup vs baseline: 1.1735x; 1.0157x over previous
//
#include <hip/hip_runtime.h>

// Problem constants
#define BB 8
#define CIN 16
#define COUT 64
#define HH 32
#define WW 32
#define PH 34
#define PW 34
#define PPLANE (PH * PW) // 1156

// denom = 2*N_EKV*VT = 0.075. Everything pre-scaled into log2-units:
//   xp = x * C,  th' = clip(theta,1,8) * C,  C = log2(e)/0.075
//   b1 = xp - th' = (x-theta)*C;  b2 = b1 - 0.1*C  => e2 = e1 * 2^(-0.1*C)
// Reference clip(a,-50,20) == post-log l = min(log2(1+2^b), B_HI) (fp32-exact:
// b >= B_HI -> log2(1+2^b)==b; b <= -30 -> 1+2^b rounds to 1 -> l=0).
// d >= 1.6: both l's hit B_HI -> cancel exactly (matches reference's clip).
// d <= -0.72 (b1 <= -13.85): f < 5e-9 -> skip via wave-uniform branch.
#define SCALE_C 19.235933878519388f /* (1/0.075)*log2(e) */
#define K2E 0.26359713811472845f    /* 2^(-0.1*SCALE_C) = e^(-4/3) */
#define B_HI 28.85390081777927f     /* 20*log2e */
#define WINLO_S (-13.849872392533959f) /* -0.72 * SCALE_C */
// final scale: ln2^2 * ALPHA * R (times runtime `scale`)
#define OUT_CONST (0.4804530139182014f * 0.05625f * 0.1f)

#define EXP2F(x) __builtin_amdgcn_exp2f(x)
#define LOG2F(x) __builtin_amdgcn_logf(x)

#define NTH (COUT * CIN * 9) // 9216

// blocks 0..577: pad+prescale x into xp ([8][16][34][34]);
// blocks 578..613: prescale clipped theta (9216 elems).
__global__ __launch_bounds__(256) void init_kernel(const float* __restrict__ x,
                                                   const float* __restrict__ theta,
                                                   float* __restrict__ xp,
                                                   float* __restrict__ thp) {
    if (blockIdx.x < 578) {
        int idx = blockIdx.x * 256 + threadIdx.x; // 578*256 = 147968 exactly
        int c = idx / PPLANE;
        int r = idx - c * PPLANE;
        int y = r / PW;
        int xc = r - y * PW;
        float v = 0.0f;
        if (y >= 1 && y <= HH && xc >= 1 && xc <= WW) {
            v = x[c * (HH * WW) + (y - 1) * WW + (xc - 1)] * SCALE_C;
        }
        xp[idx] = v;
    } else {
        int i = (blockIdx.x - 578) * 256 + threadIdx.x;
        if (i < NTH) {
            thp[i] = fminf(fmaxf(theta[i], 1.0f), 8.0f) * SCALE_C;
        }
    }
}

__device__ __forceinline__ void load9(const float* __restrict__ p, float* v) {
#pragma unroll
    for (int dy = 0; dy < 3; ++dy)
#pragma unroll
        for (int dx = 0; dx < 3; ++dx)
            v[dy * 3 + dx] = p[dy * PW + dx];
}

// thp indices are block-uniform -> s_load; sub/cmp use the SGPR operand.
// Untaken tap: v_sub + v_cmp + s_cbranch.
__device__ __forceinline__ void compute9(const float* v, const float* __restrict__ thp,
                                         float* acc) {
#pragma unroll
    for (int k = 0; k < 9; ++k) {
        float b1 = v[k] - thp[k];
        if (__any(b1 > WINLO_S)) {
            float e1 = EXP2F(b1);
            float e2 = e1 * K2E;
            float l1 = fminf(LOG2F(1.0f + e1), B_HI);
            float l2 = fminf(LOG2F(1.0f + e2), B_HI);
            float a = acc[k % 3];
            a = fmaf(l1, l1, a);
            a = fmaf(-l2, l2, a);
            acc[k % 3] = a;
        }
    }
}

// Block mapping chosen for the MI355X round-robin dispatch (bid%8 -> XCD,
// then sequential fill within XCD: CU c of XCD j hosts bids j+8c+256m,
// m=0..7). Decode so those 8 co-resident blocks share the SAME (b,tile)
// 26KB x-slice (L1-resident; ~1.4KB hot plane in lockstep) and differ only
// in co (bits 8..10 -> cm):
//   b = bid&7 (== XCD id), tile = (bid>>3)&3, co = (bid>>8)*8 + ((bid>>5)&7)
// Per-XCD L2 then holds just one 74KB batch slice of xp.
__global__ __launch_bounds__(256, 8) void ekv_kernel(const float* __restrict__ xp,
                                                     const float* __restrict__ thp,
                                                     const float* __restrict__ scale,
                                                     float* __restrict__ out) {
    int bid = blockIdx.x;
    int b = bid & 7;
    int tile = (bid >> 3) & 3;
    int cl = (bid >> 5) & 7;
    int cm = bid >> 8;
    int co = cm * 8 + cl;

    int t = threadIdx.x;
    int ow = t & 31;
    int oh = tile * 8 + (t >> 5);

    const float* thc = thp + co * (CIN * 9);
    const float* p0 = xp + (size_t)b * (CIN * PPLANE) + oh * PW + ow;

    float acc[3] = {0.0f, 0.0f, 0.0f};

    // Register ping-pong over cin: prefetch next plane's 9 taps while current
    // plane's 9 evals run.
    float va[9], vb[9];
    load9(p0, va);
#pragma unroll 1
    for (int cin = 0; cin < CIN; cin += 2) {
        load9(p0 + (cin + 1) * PPLANE, vb);
        compute9(va, thc + cin * 9, acc);
        int nc = cin + 2 < CIN ? cin + 2 : CIN - 1; // clamp: harmless re-read
        load9(p0 + nc * PPLANE, va);
        compute9(vb, thc + (cin + 1) * 9, acc);
    }

    float sc = scale[0] * (OUT_CONST);
    out[(((size_t)b * COUT + co) * HH + oh) * WW + ow] =
        (acc[0] + acc[1] + acc[2]) * sc;
}

extern "C" void kernel_launch(void* const* d_in, const int* in_sizes, int n_in,
                              void* d_out, int out_size, void* d_ws, size_t ws_size,
                              hipStream_t stream) {
    const float* x = (const float*)d_in[0];
    const float* theta = (const float*)d_in[1];
    const float* scale = (const float*)d_in[2];
    float* out = (float*)d_out;

    // ws layout: [0, 36KB) prescaled theta (9216 f32); then padded x (147968 f32)
    float* thp = (float*)d_ws;
    float* xp = thp + NTH;
    (void)ws_size;

    init_kernel<<<578 + (NTH + 255) / 256, 256, 0, stream>>>(x, theta, xp, thp);
    ekv_kernel<<<BB * 4 * COUT, 256, 0, stream>>>(xp, thp, scale, out);
}